// Round 2
// baseline (333.350 us; speedup 1.0000x reference)
//
#include <hip/hip_runtime.h>

#define B 8
#define N 2048
#define D 1024
#define C 64           // chunks along i
#define LC (N / C)     // 32 rows per chunk
#define M 6            // Taylor terms; |c_j*k_i| <~ 0.3 -> err ~1e-6
#define CH (B * 2)     // 16 independent scan chains (b x dhalf)
#define REC 512        // floats per moment per record (D/2)
#define TPB 256

// ws layout (floats):
//   kq    @ 0        : 2*B*N   = 32768
//   tA    @ 32768    : 1024*8  = 8192   (scalar moment aggregates)
//   tI    @ 40960    : 1024*8  = 8192   (scalar moment inclusives)
//   flags @ 49152    : 1024 ints        (0=empty 1=aggregate 2=inclusive)
//   pA    @ 65536    : 1024*M*REC = 3145728  (vector aggregates, ~12.6MB)
//   pI    @ 3211264  : 3145728            (vector inclusives)

// ---------------------------------------------------------------------------
// K1: k/q projections (one wave per row) + flag clear (block 0).
__global__ __launch_bounds__(256) void k_proj(const float* __restrict__ x,
                                              const float* __restrict__ wk,
                                              const float* __restrict__ wq,
                                              float* __restrict__ kq,
                                              int* __restrict__ flags) {
    if (blockIdx.x == 0) {
#pragma unroll
        for (int j = 0; j < 4; ++j) flags[threadIdx.x + j * 256] = 0;
    }
    const int wave = threadIdx.x >> 6;
    const int lane = threadIdx.x & 63;
    const int row  = blockIdx.x * 4 + wave;            // [0, B*N)
    const float4* xr  = (const float4*)(x + (size_t)row * D);
    const float4* wk4 = (const float4*)wk;
    const float4* wq4 = (const float4*)wq;
    float ak = 0.f, aq = 0.f;
#pragma unroll
    for (int t = 0; t < (D / 4) / 64; ++t) {           // 4 iterations
        float4 xv = xr[t * 64 + lane];
        float4 kv = wk4[t * 64 + lane];
        float4 qv = wq4[t * 64 + lane];
        ak += xv.x * kv.x + xv.y * kv.y + xv.z * kv.z + xv.w * kv.w;
        aq += xv.x * qv.x + xv.y * qv.y + xv.z * qv.z + xv.w * qv.w;
    }
#pragma unroll
    for (int off = 32; off > 0; off >>= 1) {
        ak += __shfl_down(ak, off, 64);
        aq += __shfl_down(aq, off, 64);
    }
    if (lane == 0) {
        kq[row] = ak;
        kq[B * N + row] = aq;
    }
}

// ---------------------------------------------------------------------------
// K2: single-pass main kernel with decoupled lookback.
//     blk = chain*C + c ; chain = (b*2 + dhalf). All 1024 blocks co-resident
//     (launch_bounds caps VGPR at 128 -> >=4 blocks/CU) so spins cannot
//     deadlock regardless of dispatch order.
__global__ __launch_bounds__(TPB, 4) void k_main(
    const float* __restrict__ kq, const float* __restrict__ f,
    float* __restrict__ tA, float* __restrict__ tI,
    float* __restrict__ pA, float* __restrict__ pI,
    int* __restrict__ flags, float* __restrict__ out)
{
    const int blk   = blockIdx.x;
    const int c     = blk & (C - 1);
    const int chain = blk >> 6;
    const int b     = chain >> 1;
    const int dh    = chain & 1;
    const int tid   = threadIdx.x;
    const int d     = dh * 512 + tid * 2;              // thread owns 2 d-cols

    __shared__ float sk[LC];
    __shared__ float sq[LC];
    __shared__ int   sp0;

    if (tid < LC)                        sk[tid]      = kq[b * N + c * LC + tid];
    else if (tid >= 64 && tid < 64 + LC) sq[tid - 64] = kq[B * N + b * N + c * LC + (tid - 64)];
    __syncthreads();

    // ---- scalar chunk moments (redundant per thread; 192 FMAs, trivial)
    float ta[M] = {0.f, 0.f, 0.f, 0.f, 0.f, 0.f};
#pragma unroll
    for (int i = 0; i < LC; ++i) {
        float kk = sk[i];
        ta[0] += (kk != 0.f) ? 1.f : 0.f;
        float kp = kk;
#pragma unroll
        for (int m = 1; m < M; ++m) { ta[m] += kp; kp *= kk; }
    }

    // ---- vector chunk moments (f streamed from HBM, coalesced float2)
    const float2* fb = (const float2*)(f + (size_t)(b * N + c * LC) * D + d);
    float2 s[M];
#pragma unroll
    for (int m = 0; m < M; ++m) s[m] = make_float2(0.f, 0.f);
#pragma unroll 8
    for (int i = 0; i < LC; ++i) {
        float2 ff = fb[i * (D / 2)];
        float  kk = sk[i];
        float  w  = (kk != 0.f) ? 1.f : 0.f;
        s[0].x += w * ff.x; s[0].y += w * ff.y;
        float kp = kk;
#pragma unroll
        for (int m = 1; m < M; ++m) {
            s[m].x += kp * ff.x; s[m].y += kp * ff.y;
            kp *= kk;
        }
    }

    // ---- publish aggregate (c==0 publishes directly as inclusive)
    const size_t rec = (size_t)blk * (M * REC);
    if (c < C - 1) {                                   // last chunk: no successor
        float* vd = (c == 0) ? pI : pA;
        float* td = (c == 0) ? tI : tA;
#pragma unroll
        for (int m = 0; m < M; ++m)
            ((float2*)(vd + rec + (size_t)m * REC))[tid] = s[m];
        if (tid == 0) {
#pragma unroll
            for (int m = 0; m < M; ++m) td[blk * 8 + m] = ta[m];
        }
        __syncthreads();                               // drains stores (vmcnt0)
        if (tid == 0) {
            __threadfence();                           // L2 writeback to agent scope
            __hip_atomic_store(&flags[blk], (c == 0) ? 2 : 1,
                               __ATOMIC_RELAXED, __HIP_MEMORY_SCOPE_AGENT);
        }
    }

    // ---- lookback: exclusive prefix, accumulated in FORWARD order so the
    //      association is bit-identical to the old serial K3 scan.
    float2 run[M];
    float  tr[M];
#pragma unroll
    for (int m = 0; m < M; ++m) { run[m] = make_float2(0.f, 0.f); tr[m] = 0.f; }

    if (c > 0) {
        if (tid == 0) {
            int p = c - 1;
            for (;;) {
                int st = __hip_atomic_load(&flags[chain * C + p],
                                           __ATOMIC_RELAXED, __HIP_MEMORY_SCOPE_AGENT);
                if (st == 2) break;                    // inclusive available here
                if (st == 1) { --p; }                  // aggregate only: keep walking
                else __builtin_amdgcn_s_sleep(2);      // not published yet: wait
            }
            sp0 = p;
        }
        __syncthreads();
        const int p0 = sp0;
        // one acquire to order the data loads below (invalidates L1/L2 once)
        (void)__hip_atomic_load(&flags[chain * C + p0],
                                __ATOMIC_ACQUIRE, __HIP_MEMORY_SCOPE_AGENT);

        const size_t recP = (size_t)(chain * C + p0) * (M * REC);
#pragma unroll
        for (int m = 0; m < M; ++m)
            run[m] = ((const float2*)(pI + recP + (size_t)m * REC))[tid];
#pragma unroll
        for (int m = 0; m < M; ++m) tr[m] = tI[(chain * C + p0) * 8 + m];

        for (int p = p0 + 1; p < c; ++p) {
            const size_t rp = (size_t)(chain * C + p) * (M * REC);
#pragma unroll
            for (int m = 0; m < M; ++m) {
                float2 v = ((const float2*)(pA + rp + (size_t)m * REC))[tid];
                run[m].x += v.x; run[m].y += v.y;
            }
#pragma unroll
            for (int m = 0; m < M; ++m) tr[m] += tA[(chain * C + p) * 8 + m];
        }

        // publish inclusive so successors can stop their walk early
        if (c < C - 1) {
#pragma unroll
            for (int m = 0; m < M; ++m) {
                float2 v;
                v.x = run[m].x + s[m].x;
                v.y = run[m].y + s[m].y;
                ((float2*)(pI + rec + (size_t)m * REC))[tid] = v;
            }
            if (tid == 0) {
#pragma unroll
                for (int m = 0; m < M; ++m) tI[blk * 8 + m] = tr[m] + ta[m];
            }
            __syncthreads();
            if (tid == 0) {
                __threadfence();
                __hip_atomic_store(&flags[blk], 2,
                                   __ATOMIC_RELAXED, __HIP_MEMORY_SCOPE_AGENT);
            }
        }
    }

    // ---- output pass: local scan from exclusive prefix + Horner + store.
    //      f re-read hits L2/L3 (tile was just streamed). Same op order as K4.
    float2* ob = (float2*)(out + (size_t)(b * N + c * LC) * D + d);
#pragma unroll 4
    for (int i = 0; i < LC; ++i) {
        float2 ff = fb[i * (D / 2)];
        float  kk = sk[i];
        float  qq = sq[i];
        float  w  = (kk != 0.f) ? 1.f : 0.f;
        tr[0] += w;
        run[0].x += w * ff.x; run[0].y += w * ff.y;
        float kp = kk;
#pragma unroll
        for (int m = 1; m < M; ++m) {
            tr[m] += kp;
            run[m].x += kp * ff.x; run[m].y += kp * ff.y;
            kp *= kk;
        }
        const float cj = qq * 0.03125f;
        const float g2 = cj * 0.5f;
        const float g3 = cj * (1.0f / 3.0f);
        const float g4 = cj * 0.25f;
        const float g5 = cj * 0.2f;
        float Z = ((((tr[5] * g5 + tr[4]) * g4 + tr[3]) * g3 + tr[2]) * g2 + tr[1]) * cj + tr[0];
        float rz = __builtin_amdgcn_rcpf(Z);
        float2 o;
        o.x = (((((run[5].x * g5 + run[4].x) * g4 + run[3].x) * g3 + run[2].x) * g2 + run[1].x) * cj + run[0].x) * rz;
        o.y = (((((run[5].y * g5 + run[4].y) * g4 + run[3].y) * g3 + run[2].y) * g2 + run[1].y) * cj + run[0].y) * rz;
        ob[i * (D / 2)] = o;
    }
}

// ---------------------------------------------------------------------------
extern "C" void kernel_launch(void* const* d_in, const int* in_sizes, int n_in,
                              void* d_out, int out_size, void* d_ws, size_t ws_size,
                              hipStream_t stream) {
    (void)in_sizes; (void)n_in; (void)out_size; (void)ws_size;
    const float* x  = (const float*)d_in[0];
    const float* f  = (const float*)d_in[1];
    const float* wk = (const float*)d_in[2];
    const float* wq = (const float*)d_in[3];
    float* out = (float*)d_out;
    float* ws  = (float*)d_ws;

    float* kq    = ws;
    float* tA    = ws + 32768;
    float* tI    = ws + 40960;
    int*   flags = (int*)(ws + 49152);
    float* pA    = ws + 65536;
    float* pI    = ws + 65536 + 3145728;

    hipLaunchKernelGGL(k_proj, dim3(B * N / 4), dim3(256), 0, stream, x, wk, wq, kq, flags);
    hipLaunchKernelGGL(k_main, dim3(CH * C),    dim3(TPB), 0, stream, kq, f, tA, tI, pA, pI, flags, out);
}

// Round 3
// 197.425 us; speedup vs baseline: 1.6885x; 1.6885x over previous
//
#include <hip/hip_runtime.h>

#define B 8
#define N 2048
#define D 1024
#define C 64           // chunks along i
#define LC (N / C)     // 32 rows per chunk
#define M 6            // Taylor terms

// ws layout (floats):
//   kq   @ 0     : 2*B*N = 32768   (k then q)
//   part @ 65536 : B*C*M*D = 3145728 floats (~12.6 MB)

// ---------------------------------------------------------------------------
// K1: k[b,n] = dot(x[b,n,:], wk), q likewise. One wave per row.
__global__ __launch_bounds__(256) void k_proj(const float* __restrict__ x,
                                              const float* __restrict__ wk,
                                              const float* __restrict__ wq,
                                              float* __restrict__ kq) {
    const int wave = threadIdx.x >> 6;
    const int lane = threadIdx.x & 63;
    const int row  = blockIdx.x * 4 + wave;            // [0, B*N)
    const float4* xr  = (const float4*)(x + (size_t)row * D);
    const float4* wk4 = (const float4*)wk;
    const float4* wq4 = (const float4*)wq;
    float ak = 0.f, aq = 0.f;
#pragma unroll
    for (int t = 0; t < (D / 4) / 64; ++t) {           // 4 iterations
        float4 xv = xr[t * 64 + lane];
        float4 kv = wk4[t * 64 + lane];
        float4 qv = wq4[t * 64 + lane];
        ak += xv.x * kv.x + xv.y * kv.y + xv.z * kv.z + xv.w * kv.w;
        aq += xv.x * qv.x + xv.y * qv.y + xv.z * qv.z + xv.w * qv.w;
    }
#pragma unroll
    for (int off = 32; off > 0; off >>= 1) {
        ak += __shfl_down(ak, off, 64);
        aq += __shfl_down(aq, off, 64);
    }
    if (lane == 0) {
        kq[row] = ak;
        kq[B * N + row] = aq;
    }
}

// ---------------------------------------------------------------------------
// K2: chunk partial moments. Block = (b,c), 256 threads, thread owns 1 float4
//     column of D. part[(b*C+c)*M + m][D] — same layout/order as baseline.
__global__ __launch_bounds__(256) void k_part(const float* __restrict__ kq,
                                              const float* __restrict__ f,
                                              float* __restrict__ part) {
    const int c   = blockIdx.x & (C - 1);
    const int b   = blockIdx.x >> 6;
    const int tid = threadIdx.x;

    __shared__ float sk[LC];
    if (tid < LC) sk[tid] = kq[b * N + c * LC + tid];
    __syncthreads();

    const float4* fb = (const float4*)(f + (size_t)(b * N + c * LC) * D) + tid;
    float4 s[M];
#pragma unroll
    for (int m = 0; m < M; ++m) s[m] = make_float4(0.f, 0.f, 0.f, 0.f);
#pragma unroll 8
    for (int i = 0; i < LC; ++i) {
        float4 ff = fb[i * (D / 4)];
        float  kk = sk[i];
        float  w  = (kk != 0.0f) ? 1.0f : 0.0f;
        s[0].x += w * ff.x; s[0].y += w * ff.y; s[0].z += w * ff.z; s[0].w += w * ff.w;
        float kp = kk;
#pragma unroll
        for (int m = 1; m < M; ++m) {
            s[m].x += kp * ff.x; s[m].y += kp * ff.y;
            s[m].z += kp * ff.z; s[m].w += kp * ff.w;
            kp *= kk;
        }
    }
    float4* pb = (float4*)(part + ((size_t)(b * C + c) * M) * D) + tid;
#pragma unroll
    for (int m = 0; m < M; ++m) pb[m * (D / 4)] = s[m];
}

// ---------------------------------------------------------------------------
// K3: in-place exclusive scan of part over c. One float column per thread:
//     B*M*D = 49152 threads = 192 blocks. Record stride M*D floats.
__global__ __launch_bounds__(256) void k_scan(float* __restrict__ part) {
    const int gid  = blockIdx.x * 256 + threadIdx.x;   // [0, B*M*D)
    const int d    = gid & (D - 1);
    const int rest = gid >> 10;                        // [0, 48)
    const int m    = rest % M;
    const int b    = rest / M;
    const size_t base = ((size_t)(b * C) * M + m) * D + d;
    const size_t cs   = (size_t)M * D;                 // floats per chunk record
    float run = 0.f;
#pragma unroll 1
    for (int c0 = 0; c0 < C; c0 += 8) {
        float buf[8];
#pragma unroll
        for (int j = 0; j < 8; ++j) buf[j] = part[base + (size_t)(c0 + j) * cs];
#pragma unroll
        for (int j = 0; j < 8; ++j) {
            float v = buf[j];
            part[base + (size_t)(c0 + j) * cs] = run;
            run += v;
        }
    }
}

// ---------------------------------------------------------------------------
// K4: output. Block = (b,c), 256 threads. Wave 0 recomputes the scalar
//     exclusive prefix Tc bit-identically to the old scanT (lane = chunk,
//     32-row serial partials + Kogge-Stone shfl_up scan, take lane c).
__global__ __launch_bounds__(256) void k_out(const float* __restrict__ kq,
                                             const float* __restrict__ f,
                                             const float* __restrict__ part,
                                             float* __restrict__ out) {
    const int c   = blockIdx.x & (C - 1);
    const int b   = blockIdx.x >> 6;
    const int tid = threadIdx.x;

    __shared__ float sk[LC];
    __shared__ float sq[LC];
    __shared__ float sT[M];

    if (tid < 64) {
        // scalar chunk moments for chunk 'tid', rows tid*LC .. +LC
        float tm[M] = {0.f, 0.f, 0.f, 0.f, 0.f, 0.f};
        const float* kb = kq + b * N + tid * LC;
#pragma unroll
        for (int i = 0; i < LC; ++i) {
            float kk = kb[i];
            tm[0] += (kk != 0.0f) ? 1.0f : 0.0f;
            float kp = kk;
#pragma unroll
            for (int m = 1; m < M; ++m) { tm[m] += kp; kp *= kk; }
        }
#pragma unroll
        for (int m = 0; m < M; ++m) {
            float v = tm[m];
            const float orig = v;
#pragma unroll
            for (int off = 1; off < 64; off <<= 1) {
                float nv = __shfl_up(v, off, 64);
                if (tid >= off) v += nv;
            }
            if (tid == c) sT[m] = v - orig;            // exclusive prefix @ chunk c
        }
    } else if (tid < 64 + LC) {
        sk[tid - 64] = kq[b * N + c * LC + (tid - 64)];
    } else if (tid >= 128 && tid < 128 + LC) {
        sq[tid - 128] = kq[B * N + b * N + c * LC + (tid - 128)];
    }
    __syncthreads();

    float4 s[M];
    float  t[M];
    const float4* pb = (const float4*)(part + ((size_t)(b * C + c) * M) * D) + tid;
#pragma unroll
    for (int m = 0; m < M; ++m) s[m] = pb[m * (D / 4)];
#pragma unroll
    for (int m = 0; m < M; ++m) t[m] = sT[m];

    const float4* fb = (const float4*)(f + (size_t)(b * N + c * LC) * D) + tid;
    float4*       ob = (float4*)(out + (size_t)(b * N + c * LC) * D) + tid;

#pragma unroll 4
    for (int i = 0; i < LC; ++i) {
        float4 ff = fb[i * (D / 4)];
        float  kk = sk[i];
        float  qq = sq[i];
        float  w  = (kk != 0.0f) ? 1.0f : 0.0f;
        t[0] += w;
        s[0].x += w * ff.x; s[0].y += w * ff.y; s[0].z += w * ff.z; s[0].w += w * ff.w;
        float kp = kk;
#pragma unroll
        for (int m = 1; m < M; ++m) {
            t[m] += kp;
            s[m].x += kp * ff.x; s[m].y += kp * ff.y;
            s[m].z += kp * ff.z; s[m].w += kp * ff.w;
            kp *= kk;
        }
        const float cj = qq * 0.03125f;
        const float g2 = cj * 0.5f;
        const float g3 = cj * (1.0f / 3.0f);
        const float g4 = cj * 0.25f;
        const float g5 = cj * 0.2f;
        float Z = ((((t[5] * g5 + t[4]) * g4 + t[3]) * g3 + t[2]) * g2 + t[1]) * cj + t[0];
        float rz = __builtin_amdgcn_rcpf(Z);
        float4 o;
        o.x = (((((s[5].x * g5 + s[4].x) * g4 + s[3].x) * g3 + s[2].x) * g2 + s[1].x) * cj + s[0].x) * rz;
        o.y = (((((s[5].y * g5 + s[4].y) * g4 + s[3].y) * g3 + s[2].y) * g2 + s[1].y) * cj + s[0].y) * rz;
        o.z = (((((s[5].z * g5 + s[4].z) * g4 + s[3].z) * g3 + s[2].z) * g2 + s[1].z) * cj + s[0].z) * rz;
        o.w = (((((s[5].w * g5 + s[4].w) * g4 + s[3].w) * g3 + s[2].w) * g2 + s[1].w) * cj + s[0].w) * rz;
        ob[i * (D / 4)] = o;
    }
}

// ---------------------------------------------------------------------------
extern "C" void kernel_launch(void* const* d_in, const int* in_sizes, int n_in,
                              void* d_out, int out_size, void* d_ws, size_t ws_size,
                              hipStream_t stream) {
    (void)in_sizes; (void)n_in; (void)out_size; (void)ws_size;
    const float* x  = (const float*)d_in[0];
    const float* f  = (const float*)d_in[1];
    const float* wk = (const float*)d_in[2];
    const float* wq = (const float*)d_in[3];
    float* out = (float*)d_out;
    float* ws  = (float*)d_ws;

    float* kq   = ws;
    float* part = ws + 65536;

    hipLaunchKernelGGL(k_proj, dim3(B * N / 4),     dim3(256), 0, stream, x, wk, wq, kq);
    hipLaunchKernelGGL(k_part, dim3(B * C),         dim3(256), 0, stream, kq, f, part);
    hipLaunchKernelGGL(k_scan, dim3(B * M * D / 256), dim3(256), 0, stream, part);
    hipLaunchKernelGGL(k_out,  dim3(B * C),         dim3(256), 0, stream, kq, f, part, out);
}